// Round 3
// baseline (109.239 us; speedup 1.0000x reference)
//
#include <hip/hip_runtime.h>

// RenderingModel: scatter-add of 64x64 filters at N particle positions onto a
// 512x512 canvas (cropped). Gather formulation: each block owns a 32x32 output
// tile AND a 512-particle segment (grid.z). Phase 1 compacts hits into LDS;
// phase 2 accumulates in registers; epilogue combines segments with global
// fp32 atomicAdd (d_out zeroed via hipMemsetAsync).
//
// R2 -> R3 restructure: 128 threads/block, each thread owns 8 contiguous
// output rows (32 x-lanes * 4 y-banks * 8 rows = 32x32 tile). Per hit a
// thread issues 8 loads off ONE base address (row offsets q*256B fit the
// 13-bit global-load immediate), doubling per-wave MLP and halving
// VALU-inst per useful load vs the 4-load version. 16 segments -> 4096
// blocks of 2 waves -> 16 blocks/CU = 32 waves/CU (100% occupancy cap).

#define H_  512
#define W_  512
#define FH_ 64
#define FW_ 64
#define TILE_ 32
#define THREADS_ 128
#define SEG_LEN_ 512   // particles per segment; LDS list sized to this

__global__ __launch_bounds__(THREADS_, 8)
void render_tile_kernel(const int* __restrict__ phw,
                        const float* __restrict__ filters,
                        float* __restrict__ out, int n) {
    __shared__ unsigned int s_list[SEG_LEN_];
    __shared__ int s_cnt;

    const int t   = threadIdx.x;
    const int tx0 = blockIdx.x * TILE_;
    const int ty0 = blockIdx.y * TILE_;
    const int k0  = blockIdx.z * SEG_LEN_;
    const int k1  = (k0 + SEG_LEN_ < n) ? (k0 + SEG_LEN_) : n;

    if (t == 0) s_cnt = 0;
    __syncthreads();

    // ---- Phase 1: bbox test + compaction of this segment into LDS ----
    // Particle (part,row,col) touches output y in [row-32, row+31],
    // x in [col-32, col+31]. Tile covers [ty0, ty0+31] x [tx0, tx0+31].
    for (int k = k0 + t; k < k1; k += THREADS_) {
        const int part = phw[k * 3 + 0];
        const int row  = phw[k * 3 + 1];
        const int col  = phw[k * 3 + 2];
        const bool hit =
            (row >= ty0 - (FH_ / 2 - 1)) && (row <= ty0 + TILE_ - 1 + FH_ / 2) &&
            (col >= tx0 - (FW_ / 2 - 1)) && (col <= tx0 + TILE_ - 1 + FW_ / 2);
        if (hit) {
            const int idx = atomicAdd(&s_cnt, 1);
            // pack: part(8b) | row(9b) | col(9b)
            s_list[idx] = ((unsigned)part << 18) | ((unsigned)row << 9) | (unsigned)col;
        }
    }
    __syncthreads();
    const int cnt = s_cnt;

    // ---- Phase 2: accumulate owned pixels in registers ----
    // Thread t owns pixels (x = tx0 + (t&31), y = ty0 + (t>>5)*8 + q), q=0..7.
    const int xl    = t & 31;
    const int yb    = t >> 5;              // 0..3
    const int x     = tx0 + xl;
    const int ybase = ty0 + yb * 8;        // first owned output row

    float acc[8] = {0.f, 0.f, 0.f, 0.f, 0.f, 0.f, 0.f, 0.f};

#pragma unroll 2
    for (int k = 0; k < cnt; ++k) {
        const unsigned v = s_list[k];
        const int part = (int)(v >> 18);
        const int row  = (int)((v >> 9) & 511u);
        const int col  = (int)(v & 511u);

        const int j = x - col + (FW_ / 2);     // filter column, same for all q
        if ((unsigned)j < (unsigned)FW_) {
            const float* f = filters + part * (FH_ * FW_) + j;
            const int i0 = ybase - row + (FH_ / 2);   // filter row for q=0
#pragma unroll
            for (int q = 0; q < 8; ++q) {
                const int i = i0 + q;                 // contiguous rows
                if ((unsigned)i < (unsigned)FH_) acc[q] += f[i * FW_];
            }
        }
    }

    // ---- Epilogue: combine segments via device-scope fp32 atomics ----
#pragma unroll
    for (int q = 0; q < 8; ++q) {
        atomicAdd(&out[(ybase + q) * W_ + x], acc[q]);
    }
}

extern "C" void kernel_launch(void* const* d_in, const int* in_sizes, int n_in,
                              void* d_out, int out_size, void* d_ws, size_t ws_size,
                              hipStream_t stream) {
    const int*   phw     = (const int*)d_in[0];
    const float* filters = (const float*)d_in[1];
    float*       out     = (float*)d_out;
    const int n = in_sizes[0] / 3;

    // Output is accumulated with atomics -> must start from zero every call
    // (harness poisons d_out with 0xAA). Async memset is graph-capture safe.
    hipMemsetAsync(out, 0, (size_t)H_ * W_ * sizeof(float), stream);

    const int segs = (n + SEG_LEN_ - 1) / SEG_LEN_;
    dim3 grid(W_ / TILE_, H_ / TILE_, segs);
    render_tile_kernel<<<grid, THREADS_, 0, stream>>>(phw, filters, out, n);
}

// Round 4
// 81.697 us; speedup vs baseline: 1.3371x; 1.3371x over previous
//
#include <hip/hip_runtime.h>

// RenderingModel: scatter-add of 64x64 filters at N particle positions onto a
// 512x512 canvas (cropped). Gather formulation: each block owns a 32x32 output
// tile AND a 1024-particle segment (grid.z = 8). Phase 1 compacts hits into
// LDS; phase 2 accumulates in registers; epilogue combines segments with
// global fp32 atomicAdd (d_out zeroed via hipMemsetAsync).
//
// R3 -> R4: back to the R2 winner shape (256 thr, 4 rows/thread, 8 segments =
// 2M atomics, not R3's 4.2M). Phase-2 rewritten latency-first:
//  - hit entries are wave-uniform -> uint4 LDS read + readfirstlane: part/row/
//    col live in SGPRs, loads become SGPR-base + small vector offset.
//  - loads are BRANCHLESS: i,j clamped into [0,63] (v_med3), load always
//    issues (address always valid), out-of-range contribution killed by a
//    value select. 16 independent unconditional loads per 4-hit batch per
//    thread -> compiler can keep them all in flight; no divergent branches.

#define H_  512
#define W_  512
#define FH_ 64
#define FW_ 64
#define TILE_ 32
#define THREADS_ 256
#define SEG_LEN_ 1024   // particles per segment; LDS list sized to this

__device__ __forceinline__ int clamp63(int v) {
    return min(max(v, 0), 63);   // -> v_med3_i32
}

__global__ __launch_bounds__(THREADS_, 8)
void render_tile_kernel(const int* __restrict__ phw,
                        const float* __restrict__ filters,
                        float* __restrict__ out, int n) {
    __shared__ unsigned int s_list[SEG_LEN_];
    __shared__ int s_cnt;

    const int t   = threadIdx.x;
    const int tx0 = blockIdx.x * TILE_;
    const int ty0 = blockIdx.y * TILE_;
    const int k0  = blockIdx.z * SEG_LEN_;
    const int k1  = (k0 + SEG_LEN_ < n) ? (k0 + SEG_LEN_) : n;

    if (t == 0) s_cnt = 0;
    __syncthreads();

    // ---- Phase 1: bbox test + compaction of this segment into LDS ----
    for (int k = k0 + t; k < k1; k += THREADS_) {
        const int part = phw[k * 3 + 0];
        const int row  = phw[k * 3 + 1];
        const int col  = phw[k * 3 + 2];
        const bool hit =
            (row >= ty0 - (FH_ / 2 - 1)) && (row <= ty0 + TILE_ - 1 + FH_ / 2) &&
            (col >= tx0 - (FW_ / 2 - 1)) && (col <= tx0 + TILE_ - 1 + FW_ / 2);
        if (hit) {
            const int idx = atomicAdd(&s_cnt, 1);
            // pack: part(8b) | row(9b) | col(9b)
            s_list[idx] = ((unsigned)part << 18) | ((unsigned)row << 9) | (unsigned)col;
        }
    }
    __syncthreads();
    const int cnt = s_cnt;

    // ---- Phase 2: accumulate owned pixels in registers ----
    // Thread t owns pixels (x = tx0 + (t&31), y = ty0 + (t>>5) + 8q), q=0..3.
    const int xl    = t & 31;
    const int yb    = t >> 5;          // 0..7
    const int x     = tx0 + xl;
    const int ybase = ty0 + yb;

    float acc0 = 0.f, acc1 = 0.f, acc2 = 0.f, acc3 = 0.f;

    // One hit's contribution: branchless (clamped address, value select).
    auto body = [&](unsigned v) {
        const int part = (int)__builtin_amdgcn_readfirstlane(v >> 18);
        const int row  = (int)__builtin_amdgcn_readfirstlane((v >> 9) & 511u);
        const int col  = (int)__builtin_amdgcn_readfirstlane(v & 511u);
        const float* __restrict__ f = filters + (part << 12);  // SGPR base

        const int  j   = x - col + (FW_ / 2);
        const int  jc  = clamp63(j);
        const bool jok = (unsigned)j < (unsigned)FW_;
        const int  i0  = ybase - row + (FH_ / 2);

        const int ia = i0;      const int ib = i0 + 8;
        const int ic = i0 + 16; const int id = i0 + 24;
        const float va = f[clamp63(ia) * FW_ + jc];   // unconditional loads,
        const float vb = f[clamp63(ib) * FW_ + jc];   // address always valid
        const float vc = f[clamp63(ic) * FW_ + jc];
        const float vd = f[clamp63(id) * FW_ + jc];
        acc0 += (jok && (unsigned)ia < (unsigned)FH_) ? va : 0.f;
        acc1 += (jok && (unsigned)ib < (unsigned)FH_) ? vb : 0.f;
        acc2 += (jok && (unsigned)ic < (unsigned)FH_) ? vc : 0.f;
        acc3 += (jok && (unsigned)id < (unsigned)FH_) ? vd : 0.f;
    };

    int k = 0;
    for (; k + 4 <= cnt; k += 4) {
        // 4 wave-uniform entries in one 16B LDS read (k%4==0 -> aligned)
        const uint4 vv = *(const uint4*)&s_list[k];
        body(vv.x); body(vv.y); body(vv.z); body(vv.w);
    }
    for (; k < cnt; ++k) body(s_list[k]);

    // ---- Epilogue: combine segments via device-scope fp32 atomics ----
    atomicAdd(&out[(ybase +  0) * W_ + x], acc0);
    atomicAdd(&out[(ybase +  8) * W_ + x], acc1);
    atomicAdd(&out[(ybase + 16) * W_ + x], acc2);
    atomicAdd(&out[(ybase + 24) * W_ + x], acc3);
}

extern "C" void kernel_launch(void* const* d_in, const int* in_sizes, int n_in,
                              void* d_out, int out_size, void* d_ws, size_t ws_size,
                              hipStream_t stream) {
    const int*   phw     = (const int*)d_in[0];
    const float* filters = (const float*)d_in[1];
    float*       out     = (float*)d_out;
    const int n = in_sizes[0] / 3;

    // Output is accumulated with atomics -> must start from zero every call
    // (harness poisons d_out with 0xAA). Async memset is graph-capture safe.
    hipMemsetAsync(out, 0, (size_t)H_ * W_ * sizeof(float), stream);

    const int segs = (n + SEG_LEN_ - 1) / SEG_LEN_;
    dim3 grid(W_ / TILE_, H_ / TILE_, segs);
    render_tile_kernel<<<grid, THREADS_, 0, stream>>>(phw, filters, out, n);
}